// Round 1
// baseline (22390.833 us; speedup 1.0000x reference)
//
#include <hip/hip_runtime.h>

#define BB 32
#define SS 64
#define TT 64
#define VV 32000
#define EE 512
#define HH 1024
#define G4 4096   // 4*H
#define CHUNK 256
#define PADW 258  // 258 % 32 == 2 -> only free 2-way LDS bank aliasing

__device__ __forceinline__ float sigf(float x) { return 1.0f / (1.0f + expf(-x)); }

// ---------------------------------------------------------------------------
// init: zero LSTM states, zero out[:,0,:], build decoder step-0 input x = dec_tab[tgt[:,0]]
// ---------------------------------------------------------------------------
__global__ void init_all(float* __restrict__ hA, float* __restrict__ cA,
                         float* __restrict__ hB, float* __restrict__ cB,
                         float* __restrict__ out, float* __restrict__ xcur,
                         const int* __restrict__ tgt, const float* __restrict__ dec_tab)
{
    int idx = blockIdx.x * 256 + threadIdx.x;
    if (idx < BB * HH) { hA[idx] = 0.f; cA[idx] = 0.f; hB[idx] = 0.f; cB[idx] = 0.f; }
    if (idx < BB * VV) {
        int b = idx / VV, v = idx % VV;
        out[(long)b * (TT * (long)VV) + v] = 0.f;   // t = 0 slice
    }
    if (idx < BB * EE) {
        int b = idx >> 9, e = idx & 511;
        int tk = tgt[b * TT];                        // tgt[:,0]
        xcur[idx] = tk ? dec_tab[(long)tk * EE + e] : 0.f;
    }
}

// ---------------------------------------------------------------------------
// pre-embed all encoder inputs: xs[t][b][e] = enc_tab[src[b][t]] (row 0 zeroed)
// ---------------------------------------------------------------------------
__global__ void embed_src(const int* __restrict__ src, const float* __restrict__ tab,
                          float* __restrict__ xs)
{
    int idx = blockIdx.x * 256 + threadIdx.x;    // [t][b][e], 64*32*512
    int e = idx & 511, b = (idx >> 9) & 31, t = idx >> 14;
    int tk = src[b * SS + t];
    xs[idx] = tk ? tab[(long)tk * EE + e] : 0.f;
}

// ---------------------------------------------------------------------------
// skinny GEMM partial: gates_partial[kc][b][j] = sum_{k in chunk} in[b][k] * W[j][k]
// Input rows are the concatenation [X (KE cols) ; H (1024 cols)]; each 256-col
// chunk lies entirely in one part (KE % 256 == 0). Lane = batch row (b=lane&31),
// 8 j's per lane; weight rows streamed as half-wave-uniform float4 loads.
// ---------------------------------------------------------------------------
__global__ __launch_bounds__(512) void gemm_skinny(
    const float* __restrict__ X, int KE,
    const float* __restrict__ Hs,
    const float* __restrict__ Wx, const float* __restrict__ Wh,
    float* __restrict__ P, int jblocks)
{
    __shared__ float hs[BB][PADW];
    int jb = blockIdx.x % jblocks;
    int kc = blockIdx.x / jblocks;
    int k0 = kc * CHUNK;

    const float* src; const float* wsrc; int stride; int col0;
    if (k0 < KE) { src = X;  wsrc = Wx; stride = KE; col0 = k0; }
    else         { src = Hs; wsrc = Wh; stride = HH; col0 = k0 - KE; }

    {   // stage 32 x 256 input tile into LDS (padded rows)
        int sb = threadIdx.x >> 4;
        int c0 = (threadIdx.x & 15) << 4;
        const float4* s4 = reinterpret_cast<const float4*>(src + sb * stride + col0 + c0);
        float4 v0 = s4[0], v1 = s4[1], v2 = s4[2], v3 = s4[3];
        float* d = &hs[sb][c0];
        d[0]=v0.x; d[1]=v0.y; d[2]=v0.z; d[3]=v0.w;
        d[4]=v1.x; d[5]=v1.y; d[6]=v1.z; d[7]=v1.w;
        d[8]=v2.x; d[9]=v2.y; d[10]=v2.z; d[11]=v2.w;
        d[12]=v3.x; d[13]=v3.y; d[14]=v3.z; d[15]=v3.w;
    }
    __syncthreads();

    int lane = threadIdx.x & 63;
    int wid  = threadIdx.x >> 6;
    int rb   = lane & 31;
    int hf   = lane >> 5;
    int jbase = jb * 128 + wid * 16 + hf * 8;

    const float* wr[8];
#pragma unroll
    for (int q = 0; q < 8; ++q) wr[q] = wsrc + (long)(jbase + q) * stride + col0;
    float acc[8];
#pragma unroll
    for (int q = 0; q < 8; ++q) acc[q] = 0.f;

#pragma unroll 2
    for (int kk = 0; kk < CHUNK; kk += 4) {
        float2 h01 = *reinterpret_cast<const float2*>(&hs[rb][kk]);
        float2 h23 = *reinterpret_cast<const float2*>(&hs[rb][kk + 2]);
#pragma unroll
        for (int q = 0; q < 8; ++q) {
            float4 w4 = *reinterpret_cast<const float4*>(wr[q] + kk);
            acc[q] += h01.x * w4.x + h01.y * w4.y + h23.x * w4.z + h23.y * w4.w;
        }
    }

    float* dst = P + ((long)kc * BB + rb) * G4 + jbase;
#pragma unroll
    for (int q = 0; q < 8; ++q) dst[q] = acc[q];
}

// ---------------------------------------------------------------------------
// reduce k-split partials + bias, apply LSTM cell, update h/c (and ys if given)
// ---------------------------------------------------------------------------
__global__ void reduce_cell(const float* __restrict__ P, int nc,
                            const float* __restrict__ bias,
                            float* __restrict__ h, float* __restrict__ c,
                            float* __restrict__ ys)
{
    int idx = blockIdx.x * 256 + threadIdx.x;   // 0 .. 32*1024-1
    int b = idx >> 10, kk = idx & 1023;
    float gi = bias[kk];
    float gf = bias[HH + kk];
    float gg = bias[2 * HH + kk];
    float go = bias[3 * HH + kk];
    for (int cc = 0; cc < nc; ++cc) {
        const float* p = P + ((long)cc * BB + b) * G4;
        gi += p[kk];
        gf += p[HH + kk];
        gg += p[2 * HH + kk];
        go += p[3 * HH + kk];
    }
    float cn = sigf(gf) * c[idx] + sigf(gi) * tanhf(gg);
    float hn = sigf(go) * tanhf(cn);
    c[idx] = cn;
    h[idx] = hn;
    if (ys) ys[idx] = hn;
}

// ---------------------------------------------------------------------------
// FC: out[b][t][j] = h[b] . W[j] + bias[j]   (M=32, N=32000, K=1024)
// Same skinny pattern, full K per block (4 LDS restage rounds).
// ---------------------------------------------------------------------------
__global__ __launch_bounds__(512) void fc_logits(
    const float* __restrict__ Hs, const float* __restrict__ W,
    const float* __restrict__ bias, float* __restrict__ out, int t)
{
    __shared__ float hs[BB][PADW];
    int jb = blockIdx.x;                 // 0..249
    int lane = threadIdx.x & 63;
    int wid  = threadIdx.x >> 6;
    int rb   = lane & 31;
    int hf   = lane >> 5;
    int jbase = jb * 128 + wid * 16 + hf * 8;

    float acc[8];
#pragma unroll
    for (int q = 0; q < 8; ++q) acc[q] = 0.f;

    for (int r = 0; r < 4; ++r) {
        int k0 = r * CHUNK;
        {
            int sb = threadIdx.x >> 4;
            int c0 = (threadIdx.x & 15) << 4;
            const float4* s4 = reinterpret_cast<const float4*>(Hs + sb * HH + k0 + c0);
            float4 v0 = s4[0], v1 = s4[1], v2 = s4[2], v3 = s4[3];
            float* d = &hs[sb][c0];
            d[0]=v0.x; d[1]=v0.y; d[2]=v0.z; d[3]=v0.w;
            d[4]=v1.x; d[5]=v1.y; d[6]=v1.z; d[7]=v1.w;
            d[8]=v2.x; d[9]=v2.y; d[10]=v2.z; d[11]=v2.w;
            d[12]=v3.x; d[13]=v3.y; d[14]=v3.z; d[15]=v3.w;
        }
        __syncthreads();

        const float* wr[8];
#pragma unroll
        for (int q = 0; q < 8; ++q) wr[q] = W + (long)(jbase + q) * HH + k0;
#pragma unroll 2
        for (int kk = 0; kk < CHUNK; kk += 4) {
            float2 h01 = *reinterpret_cast<const float2*>(&hs[rb][kk]);
            float2 h23 = *reinterpret_cast<const float2*>(&hs[rb][kk + 2]);
#pragma unroll
            for (int q = 0; q < 8; ++q) {
                float4 w4 = *reinterpret_cast<const float4*>(wr[q] + kk);
                acc[q] += h01.x * w4.x + h01.y * w4.y + h23.x * w4.z + h23.y * w4.w;
            }
        }
        __syncthreads();
    }

    float* dst = out + (long)rb * (TT * (long)VV) + (long)t * VV + jbase;
#pragma unroll
    for (int q = 0; q < 8; ++q) dst[q] = acc[q] + bias[jbase + q];
}

// ---------------------------------------------------------------------------
// per-batch-row argmax over 32000 logits (first-max tie-break, = jnp.argmax),
// teacher-mask select, embed next decoder input.
// ---------------------------------------------------------------------------
__global__ void argmax_next(const float* __restrict__ out, int t,
                            const int* __restrict__ tmask, const int* __restrict__ tgt,
                            const float* __restrict__ dec_tab,
                            float* __restrict__ xcur)
{
    int b = blockIdx.x;
    const float* row = out + (long)b * (TT * (long)VV) + (long)t * VV;
    int tid = threadIdx.x;
    float bv = -3.402823466e38f;
    int bi = 0x7fffffff;
    for (int v = tid; v < VV; v += 256) {
        float x = row[v];
        if (x > bv) { bv = x; bi = v; }
    }
    __shared__ float sv[256];
    __shared__ int   si[256];
    sv[tid] = bv; si[tid] = bi;
    __syncthreads();
    for (int s = 128; s > 0; s >>= 1) {
        if (tid < s) {
            float ov = sv[tid + s]; int oi = si[tid + s];
            if (ov > sv[tid] || (ov == sv[tid] && oi < si[tid])) { sv[tid] = ov; si[tid] = oi; }
        }
        __syncthreads();
    }
    __shared__ int tok;
    if (tid == 0) {
        int teach = tmask[t];
        tok = (teach > 0) ? tgt[b * TT + t] : si[0];
    }
    __syncthreads();
    int tk = tok;
    for (int e = tid; e < EE; e += 256)
        xcur[b * EE + e] = tk ? dec_tab[(long)tk * EE + e] : 0.f;
}

// ---------------------------------------------------------------------------
extern "C" void kernel_launch(void* const* d_in, const int* in_sizes, int n_in,
                              void* d_out, int out_size, void* d_ws, size_t ws_size,
                              hipStream_t stream)
{
    const int*   src      = (const int*)d_in[0];
    const int*   tgt      = (const int*)d_in[1];
    const int*   tmask    = (const int*)d_in[2];
    const float* enc_embed= (const float*)d_in[3];
    const float* dec_embed= (const float*)d_in[4];
    const float* enc_wih0 = (const float*)d_in[5];
    const float* enc_whh0 = (const float*)d_in[6];
    const float* enc_b0   = (const float*)d_in[7];
    const float* enc_wih1 = (const float*)d_in[8];
    const float* enc_whh1 = (const float*)d_in[9];
    const float* enc_b1   = (const float*)d_in[10];
    const float* dec_wih0 = (const float*)d_in[11];
    const float* dec_whh0 = (const float*)d_in[12];
    const float* dec_b0   = (const float*)d_in[13];
    const float* dec_wih1 = (const float*)d_in[14];
    const float* dec_whh1 = (const float*)d_in[15];
    const float* dec_b1   = (const float*)d_in[16];
    const float* fc_w     = (const float*)d_in[17];
    const float* fc_b     = (const float*)d_in[18];
    float* out = (float*)d_out;

    float* ws   = (float*)d_ws;
    float* P    = ws;                    // 8*32*4096      = 1,048,576 floats
    float* hA   = P    + 1048576;        // 32*1024
    float* cA   = hA   + 32768;
    float* hB   = cA   + 32768;
    float* cB   = hB   + 32768;
    float* xcur = cB   + 32768;          // 32*512
    float* xs   = xcur + 16384;          // 64*32*512      = 1,048,576
    float* ys0  = xs   + 1048576;        // 64*32*1024     = 2,097,152
    // total ~4.34M floats (~17.4 MB) of d_ws

    init_all<<<4000, 256, 0, stream>>>(hA, cA, hB, cB, out, xcur, tgt, dec_embed);
    embed_src<<<4096, 256, 0, stream>>>(src, enc_embed, xs);

    // encoder layer 0: K = 512 + 1024 = 1536 -> 6 chunks
    for (int t = 0; t < SS; ++t) {
        gemm_skinny<<<192, 512, 0, stream>>>(xs + t * BB * EE, EE, hA,
                                             enc_wih0, enc_whh0, P, 32);
        reduce_cell<<<128, 256, 0, stream>>>(P, 6, enc_b0, hA, cA, ys0 + t * BB * HH);
    }
    // encoder layer 1: K = 1024 + 1024 = 2048 -> 8 chunks
    for (int t = 0; t < SS; ++t) {
        gemm_skinny<<<256, 512, 0, stream>>>(ys0 + t * BB * HH, HH, hB,
                                             enc_wih1, enc_whh1, P, 32);
        reduce_cell<<<128, 256, 0, stream>>>(P, 8, enc_b1, hB, cB, nullptr);
    }
    // decoder: 63 steps; states continue from encoder finals
    for (int k = 0; k < TT - 1; ++k) {
        gemm_skinny<<<192, 512, 0, stream>>>(xcur, EE, hA, dec_wih0, dec_whh0, P, 32);
        reduce_cell<<<128, 256, 0, stream>>>(P, 6, dec_b0, hA, cA, nullptr);
        gemm_skinny<<<256, 512, 0, stream>>>(hA, HH, hB, dec_wih1, dec_whh1, P, 32);
        reduce_cell<<<128, 256, 0, stream>>>(P, 8, dec_b1, hB, cB, nullptr);
        fc_logits<<<250, 512, 0, stream>>>(hB, fc_w, fc_b, out, k + 1);
        argmax_next<<<32, 256, 0, stream>>>(out, k + 1, tmask, tgt, dec_embed, xcur);
    }
}